// Round 1
// baseline (283.382 us; speedup 1.0000x reference)
//
#include <hip/hip_runtime.h>
#include <hip/hip_cooperative_groups.h>

namespace cg = cooperative_groups;

// RandomForest: 131072 samples x 64 feat, 64 trees depth 12, 8-class vote.
//
// R10 = R9's walk verbatim, but ALL THREE kernels fused into ONE cooperative
// launch. Evidence: steady-state forest = 47.8us yet measured total = 116.5us
// -> ~60us is pack kernels + per-launch overhead (~15-20us x 3 launches).
// R8->R9 showed the walk is throughput-saturated (TLP 2x -> 0%), so the
// biggest available lever is launch count, not the walk. Pack (87,360 items)
// is striped over the whole grid and overlapped with each block's X->LDS
// staging (independent of pack), then a grid.sync() gates the walk.
// Grid = min(512, occupancy*256): 2 blocks/CU @ 64KiB LDS, VGPR~32 ->
// co-resident, valid cooperative config; chunk loop covers any clamp.

constexpr int kSamples  = 131072;
constexpr int kFeat     = 64;
constexpr int kTrees    = 64;
constexpr int kInternal = 4095;
constexpr int kClasses  = 8;

constexpr int TPB  = 1024;
constexpr int SPB  = 256;                        // samples per block-chunk
constexpr int XSTR = 256;                        // dwords; f column = f<<10 bytes
constexpr int XLDS_BYTES = kFeat * XSTR * 4;     // 65536 B
constexpr int ILP  = 8;
constexpr int TREES_PER_THREAD = 16;             // 4 thread-slices per sample
constexpr int NCHUNKS = kSamples / SPB;          // 512

// Pair p covers levels 2p,2p+1; entries-before offsets {0,1,5,21,85}, 341/tree,
// stride 512 -> tree base = t<<9.
struct Pair  { float thr0, thrL, thrR; unsigned meta; };  // meta: f0|fL<<6|fR<<12
struct Sub16 { float thr10, thrL, thrR; unsigned meta; }; // +lv0..lv3 <<18,21,24,27

constexpr int kPairItems = kTrees * 341;              // 21824
constexpr int kSubItems  = kTrees * 1024;             // 65536
constexpr int kPackItems = kPairItems + kSubItems;    // 87360

__global__ __launch_bounds__(TPB, 8) void forest_all(
    const float* __restrict__ X,
    const int*   __restrict__ features,
    const float* __restrict__ thresholds,
    const int*   __restrict__ leaf_values,
    Pair*        __restrict__ pairsA,   // [64][512] (341 used)
    Sub16*       __restrict__ subsA,    // [64][1024]
    int*         __restrict__ out)
{
    extern __shared__ float xs[];                  // [64][256] feature-major
    const int tid = threadIdx.x;
    const int s   = tid & (SPB - 1);               // sample slot 0..255
    const int h   = tid >> 8;                      // forest quarter 0..3

    // ---------- Phase 0: pack tables (whole grid cooperates) ----------
    for (int g = blockIdx.x * TPB + tid; g < kPackItems; g += gridDim.x * TPB) {
        if (g < kPairItems) {
            int t = g / 341;
            int e = g - t * 341;
            int p, m;
            if      (e < 1)  { p = 0; m = e; }
            else if (e < 5)  { p = 1; m = e - 1; }
            else if (e < 21) { p = 2; m = e - 5; }
            else if (e < 85) { p = 3; m = e - 21; }
            else             { p = 4; m = e - 85; }
            int g0 = (1 << (2 * p)) - 1 + m;       // global node id at level 2p
            int b  = t * kInternal;
            Pair pr;
            pr.thr0 = thresholds[b + g0];
            pr.thrL = thresholds[b + 2 * g0 + 1];
            pr.thrR = thresholds[b + 2 * g0 + 2];
            pr.meta = (unsigned)features[b + g0]
                    | ((unsigned)features[b + 2 * g0 + 1] << 6)
                    | ((unsigned)features[b + 2 * g0 + 2] << 12);
            pairsA[(t << 9) + e] = pr;
        } else {
            int i2 = g - kPairItems;
            int t = i2 >> 10;
            int j = i2 & 1023;                     // level-10 local index
            int n10 = 1023 + j;
            int b   = t * kInternal;
            Sub16 sb;
            sb.thr10 = thresholds[b + n10];
            sb.thrL  = thresholds[b + 2 * n10 + 1];
            sb.thrR  = thresholds[b + 2 * n10 + 2];
            const int* lv = leaf_values + ((t << 12) + 4 * j);
            sb.meta = (unsigned)features[b + n10]
                    | ((unsigned)features[b + 2 * n10 + 1] << 6)
                    | ((unsigned)features[b + 2 * n10 + 2] << 12)
                    | ((unsigned)lv[0] << 18) | ((unsigned)lv[1] << 21)
                    | ((unsigned)lv[2] << 24) | ((unsigned)lv[3] << 27);
            subsA[(t << 10) + j] = sb;
        }
    }

    // ---------- Stage first X chunk (independent of pack; hides its latency) ----------
    {
        const int base0 = blockIdx.x * SPB;        // grid <= NCHUNKS guaranteed
        const float4* Xr = (const float4*)(X + (size_t)(base0 + s) * kFeat) + h * 4;
        #pragma unroll
        for (int k = 0; k < 4; ++k) {
            float4 v = Xr[k];
            int f0 = (h * 4 + k) * 4;
            xs[(f0 + 0) * XSTR + s] = v.x;
            xs[(f0 + 1) * XSTR + s] = v.y;
            xs[(f0 + 2) * XSTR + s] = v.z;
            xs[(f0 + 3) * XSTR + s] = v.w;
        }
    }

    __threadfence();                               // pack stores device-visible
    cg::this_grid().sync();                        // gate: tables complete

    const char* xb = (const char*)xs + (s << 2);   // + (f<<10) per access
    const int mofs[4] = {0, 1, 5, 21};             // shallow pair offsets

    bool first = true;
    for (int chunk = blockIdx.x; chunk < NCHUNKS; chunk += (int)gridDim.x) {
        const int base = chunk * SPB;

        if (!first) {
            // previous iteration ended with __syncthreads(); xs is dead.
            const float4* Xr = (const float4*)(X + (size_t)(base + s) * kFeat) + h * 4;
            #pragma unroll
            for (int k = 0; k < 4; ++k) {
                float4 v = Xr[k];
                int f0 = (h * 4 + k) * 4;
                xs[(f0 + 0) * XSTR + s] = v.x;
                xs[(f0 + 1) * XSTR + s] = v.y;
                xs[(f0 + 2) * XSTR + s] = v.z;
                xs[(f0 + 3) * XSTR + s] = v.w;
            }
        }
        __syncthreads();

        unsigned long long votes = 0ull;
        const int tbeg = h * TREES_PER_THREAD;
        for (int t0 = tbeg; t0 < tbeg + TREES_PER_THREAD; t0 += ILP) {
            int m[ILP];
            #pragma unroll
            for (int j = 0; j < ILP; ++j) m[j] = 0;

            #pragma unroll
            for (int p = 0; p < 4; ++p) {          // levels 0..7
                #pragma unroll
                for (int j = 0; j < ILP; ++j) {    // 8 independent chains
                    Pair pr = pairsA[((t0 + j) << 9) + mofs[p] + m[j]];
                    float x0 = *(const float*)(xb + ((pr.meta & 63u) << 10));
                    int c0 = x0 > pr.thr0 ? 1 : 0;
                    float thr1     = c0 ? pr.thrR : pr.thrL;
                    unsigned fsel  = c0 ? (pr.meta >> 12) : (pr.meta >> 6);
                    float x1 = *(const float*)(xb + ((fsel & 63u) << 10));
                    int c1 = x1 > thr1 ? 1 : 0;
                    m[j] = 4 * m[j] + 2 * c0 + c1;
                }
            }

            #pragma unroll
            for (int j = 0; j < ILP; ++j) {        // levels 8,9 (pair4)
                Pair pr = pairsA[((t0 + j) << 9) + 85 + m[j]];
                float x0 = *(const float*)(xb + ((pr.meta & 63u) << 10));
                int c0 = x0 > pr.thr0 ? 1 : 0;
                float thr1     = c0 ? pr.thrR : pr.thrL;
                unsigned fsel  = c0 ? (pr.meta >> 12) : (pr.meta >> 6);
                float x1 = *(const float*)(xb + ((fsel & 63u) << 10));
                int c1 = x1 > thr1 ? 1 : 0;
                m[j] = 4 * m[j] + 2 * c0 + c1;
            }

            #pragma unroll
            for (int j = 0; j < ILP; ++j) {        // levels 10,11 + leaf
                Sub16 sb = subsA[((t0 + j) << 10) + m[j]];
                unsigned mt = sb.meta;
                float x0 = *(const float*)(xb + ((mt & 63u) << 10));
                int c0 = x0 > sb.thr10 ? 1 : 0;
                float thr1    = c0 ? sb.thrR : sb.thrL;
                unsigned fsel = c0 ? (mt >> 12) : (mt >> 6);
                float x1 = *(const float*)(xb + ((fsel & 63u) << 10));
                int c1 = x1 > thr1 ? 1 : 0;
                int cls = (mt >> (18 + 3 * ((c0 << 1) | c1))) & 7;
                votes += 1ull << (cls << 3);
            }
        }

        // Combine 4 partial vote vectors per sample through LDS (xs dead now).
        __syncthreads();
        unsigned long long* vbuf = (unsigned long long*)xs;   // 3*256 u64 = 6 KiB
        if (h != 0) vbuf[(h - 1) * SPB + s] = votes;
        __syncthreads();
        if (h == 0) {
            votes += vbuf[s] + vbuf[SPB + s] + vbuf[2 * SPB + s];
            // argmax over 8 packed byte counters; strict '>' keeps smallest class
            int best = 0;
            int bc   = (int)(votes & 0xFFull);
            #pragma unroll
            for (int c = 1; c < kClasses; ++c) {
                int cnt = (int)((votes >> (c * 8)) & 0xFFull);
                if (cnt > bc) { bc = cnt; best = c; }
            }
            out[base + s] = best;
        }
        __syncthreads();                            // vbuf dead before next stage
        first = false;
    }
}

extern "C" void kernel_launch(void* const* d_in, const int* in_sizes, int n_in,
                              void* d_out, int out_size, void* d_ws, size_t ws_size,
                              hipStream_t stream) {
    const float* X          = (const float*)d_in[0];
    const int*   features   = (const int*)d_in[1];
    const float* thresholds = (const float*)d_in[2];
    const int*   leaves     = (const int*)d_in[3];
    int*         out        = (int*)d_out;

    Pair*  pairsA = (Pair*)d_ws;                            // 64*512*16 = 512 KiB
    Sub16* subsA  = (Sub16*)((char*)d_ws + (kTrees << 13)); // +512 KiB, 1 MiB

    (void)hipFuncSetAttribute((const void*)forest_all,
                              hipFuncAttributeMaxDynamicSharedMemorySize,
                              XLDS_BYTES);

    int maxB = 0;
    (void)hipOccupancyMaxActiveBlocksPerMultiprocessor(
        &maxB, (const void*)forest_all, TPB, XLDS_BYTES);
    if (maxB < 1) maxB = 1;
    unsigned grid = (unsigned)maxB * 256u;                  // 256 CUs on MI355X
    if (grid > (unsigned)NCHUNKS) grid = (unsigned)NCHUNKS;

    void* args[] = {(void*)&X, (void*)&features, (void*)&thresholds, (void*)&leaves,
                    (void*)&pairsA, (void*)&subsA, (void*)&out};
    (void)hipLaunchCooperativeKernel((const void*)forest_all, dim3(grid), dim3(TPB),
                                     args, (unsigned)XLDS_BYTES, stream);
}

// Round 2
// 117.718 us; speedup vs baseline: 2.4073x; 2.4073x over previous
//
#include <hip/hip_runtime.h>
#include <hip/hip_cooperative_groups.h>

namespace cg = cooperative_groups;

// RandomForest: 131072 samples x 64 feat, 64 trees depth 12, 8-class vote.
//
// R11 = single cooperative launch (R10's validated overhead win) with R9's
// walk restored to straight-line form. R10 post-mortem: wrapping the walk in
// a dynamic chunk loop made the compiler reschedule into 28 VGPRs,
// serializing the ILP-8 chain loads -> 6.4x stall blowup (VALU busy-time
// unchanged at ~23us, dur 48->310us). Fix: grid pinned to exactly
// NCHUNKS=512 (2 blocks/CU, same residency R9 ran at), each block owns
// chunk blockIdx.x, no loop, no 'first' flag. Pack is one-item-per-thread
// (524288 threads >= 87360 items), overlapped with X->LDS staging, then one
// grid sync gates the walk. Fallback to the 3-kernel plan if the
// cooperative config is rejected.

constexpr int kSamples  = 131072;
constexpr int kFeat     = 64;
constexpr int kTrees    = 64;
constexpr int kInternal = 4095;
constexpr int kClasses  = 8;

constexpr int TPB  = 1024;
constexpr int SPB  = 256;                        // samples per block
constexpr int XSTR = 256;                        // dwords; f column = f<<10 bytes
constexpr int XLDS_BYTES = kFeat * XSTR * 4;     // 65536 B
constexpr int ILP  = 8;
constexpr int TREES_PER_THREAD = 16;             // 4 thread-slices per sample
constexpr int NCHUNKS = kSamples / SPB;          // 512

// Pair p covers levels 2p,2p+1; entries-before offsets {0,1,5,21,85}, 341/tree,
// stride 512 -> tree base = t<<9.
struct Pair  { float thr0, thrL, thrR; unsigned meta; };  // meta: f0|fL<<6|fR<<12
struct Sub16 { float thr10, thrL, thrR; unsigned meta; }; // +lv0..lv3 <<18,21,24,27

constexpr int kPairItems = kTrees * 341;              // 21824
constexpr int kSubItems  = kTrees * 1024;             // 65536
constexpr int kPackItems = kPairItems + kSubItems;    // 87360

// ---------------- fused cooperative kernel ----------------

__global__ __launch_bounds__(TPB, 8) void forest_all(
    const float* __restrict__ X,
    const int*   __restrict__ features,
    const float* __restrict__ thresholds,
    const int*   __restrict__ leaf_values,
    Pair*        __restrict__ pairsA,   // [64][512] (341 used)
    Sub16*       __restrict__ subsA,    // [64][1024]
    int*         __restrict__ out)
{
    extern __shared__ float xs[];                  // [64][256] feature-major
    const int tid  = threadIdx.x;
    const int s    = tid & (SPB - 1);              // sample slot 0..255
    const int h    = tid >> 8;                     // forest quarter 0..3
    const int base = blockIdx.x * SPB;             // grid == NCHUNKS guaranteed

    // ---------- Phase 0: pack tables, one item per thread ----------
    {
        const int g = blockIdx.x * TPB + tid;      // 524288 threads >= 87360 items
        if (g < kPairItems) {
            int t = g / 341;
            int e = g - t * 341;
            int p, m;
            if      (e < 1)  { p = 0; m = e; }
            else if (e < 5)  { p = 1; m = e - 1; }
            else if (e < 21) { p = 2; m = e - 5; }
            else if (e < 85) { p = 3; m = e - 21; }
            else             { p = 4; m = e - 85; }
            int g0 = (1 << (2 * p)) - 1 + m;       // global node id at level 2p
            int b  = t * kInternal;
            Pair pr;
            pr.thr0 = thresholds[b + g0];
            pr.thrL = thresholds[b + 2 * g0 + 1];
            pr.thrR = thresholds[b + 2 * g0 + 2];
            pr.meta = (unsigned)features[b + g0]
                    | ((unsigned)features[b + 2 * g0 + 1] << 6)
                    | ((unsigned)features[b + 2 * g0 + 2] << 12);
            pairsA[(t << 9) + e] = pr;
        } else if (g < kPackItems) {
            int i2 = g - kPairItems;
            int t = i2 >> 10;
            int j = i2 & 1023;                     // level-10 local index
            int n10 = 1023 + j;
            int b   = t * kInternal;
            Sub16 sb;
            sb.thr10 = thresholds[b + n10];
            sb.thrL  = thresholds[b + 2 * n10 + 1];
            sb.thrR  = thresholds[b + 2 * n10 + 2];
            const int* lv = leaf_values + ((t << 12) + 4 * j);
            sb.meta = (unsigned)features[b + n10]
                    | ((unsigned)features[b + 2 * n10 + 1] << 6)
                    | ((unsigned)features[b + 2 * n10 + 2] << 12)
                    | ((unsigned)lv[0] << 18) | ((unsigned)lv[1] << 21)
                    | ((unsigned)lv[2] << 24) | ((unsigned)lv[3] << 27);
            subsA[(t << 10) + j] = sb;
        }
    }

    // ---------- Stage X chunk (independent of pack; hides its latency) ----------
    {
        const float4* Xr = (const float4*)(X + (size_t)(base + s) * kFeat) + h * 4;
        #pragma unroll
        for (int k = 0; k < 4; ++k) {
            float4 v = Xr[k];
            int f0 = (h * 4 + k) * 4;
            xs[(f0 + 0) * XSTR + s] = v.x;
            xs[(f0 + 1) * XSTR + s] = v.y;
            xs[(f0 + 2) * XSTR + s] = v.z;
            xs[(f0 + 3) * XSTR + s] = v.w;
        }
    }

    __threadfence();                               // pack stores device-visible
    cg::this_grid().sync();                        // gate: tables complete (implies block barrier)

    // ---------- Walk: R9 body verbatim ----------
    const char* xb = (const char*)xs + (s << 2);   // + (f<<10) per access
    unsigned long long votes = 0ull;

    const int mofs[4] = {0, 1, 5, 21};             // shallow pair offsets

    const int tbeg = h * TREES_PER_THREAD;
    for (int t0 = tbeg; t0 < tbeg + TREES_PER_THREAD; t0 += ILP) {
        int m[ILP];
        #pragma unroll
        for (int j = 0; j < ILP; ++j) m[j] = 0;

        #pragma unroll
        for (int p = 0; p < 4; ++p) {              // levels 0..7
            #pragma unroll
            for (int j = 0; j < ILP; ++j) {        // 8 independent chains
                Pair pr = pairsA[((t0 + j) << 9) + mofs[p] + m[j]];
                float x0 = *(const float*)(xb + ((pr.meta & 63u) << 10));
                int c0 = x0 > pr.thr0 ? 1 : 0;
                float thr1     = c0 ? pr.thrR : pr.thrL;
                unsigned fsel  = c0 ? (pr.meta >> 12) : (pr.meta >> 6);
                float x1 = *(const float*)(xb + ((fsel & 63u) << 10));
                int c1 = x1 > thr1 ? 1 : 0;
                m[j] = 4 * m[j] + 2 * c0 + c1;
            }
        }

        #pragma unroll
        for (int j = 0; j < ILP; ++j) {            // levels 8,9 (pair4)
            Pair pr = pairsA[((t0 + j) << 9) + 85 + m[j]];
            float x0 = *(const float*)(xb + ((pr.meta & 63u) << 10));
            int c0 = x0 > pr.thr0 ? 1 : 0;
            float thr1     = c0 ? pr.thrR : pr.thrL;
            unsigned fsel  = c0 ? (pr.meta >> 12) : (pr.meta >> 6);
            float x1 = *(const float*)(xb + ((fsel & 63u) << 10));
            int c1 = x1 > thr1 ? 1 : 0;
            m[j] = 4 * m[j] + 2 * c0 + c1;
        }

        #pragma unroll
        for (int j = 0; j < ILP; ++j) {            // levels 10,11 + leaf
            Sub16 sb = subsA[((t0 + j) << 10) + m[j]];
            unsigned mt = sb.meta;
            float x0 = *(const float*)(xb + ((mt & 63u) << 10));
            int c0 = x0 > sb.thr10 ? 1 : 0;
            float thr1    = c0 ? sb.thrR : sb.thrL;
            unsigned fsel = c0 ? (mt >> 12) : (mt >> 6);
            float x1 = *(const float*)(xb + ((fsel & 63u) << 10));
            int c1 = x1 > thr1 ? 1 : 0;
            int cls = (mt >> (18 + 3 * ((c0 << 1) | c1))) & 7;
            votes += 1ull << (cls << 3);
        }
    }

    // Combine 4 partial vote vectors per sample through LDS (xs dead now).
    __syncthreads();
    unsigned long long* vbuf = (unsigned long long*)xs;   // 3*256 u64 = 6 KiB
    if (h != 0) vbuf[(h - 1) * SPB + s] = votes;
    __syncthreads();
    if (h == 0) {
        votes += vbuf[s] + vbuf[SPB + s] + vbuf[2 * SPB + s];
        // argmax over 8 packed byte counters; strict '>' keeps smallest class
        int best = 0;
        int bc   = (int)(votes & 0xFFull);
        #pragma unroll
        for (int c = 1; c < kClasses; ++c) {
            int cnt = (int)((votes >> (c * 8)) & 0xFFull);
            if (cnt > bc) { bc = cnt; best = c; }
        }
        out[base + s] = best;
    }
}

// ---------------- fallback 3-kernel plan (R9) ----------------

__global__ __launch_bounds__(256) void pack_pairs_kernel(
    const int* __restrict__ features, const float* __restrict__ thresholds,
    Pair* __restrict__ pairsA)
{
    int i = blockIdx.x * 256 + threadIdx.x;       // over 64*341
    if (i >= kTrees * 341) return;
    int t = i / 341;
    int e = i - t * 341;
    int p, m;
    if      (e < 1)  { p = 0; m = e; }
    else if (e < 5)  { p = 1; m = e - 1; }
    else if (e < 21) { p = 2; m = e - 5; }
    else if (e < 85) { p = 3; m = e - 21; }
    else             { p = 4; m = e - 85; }
    int g0 = (1 << (2 * p)) - 1 + m;
    int b  = t * kInternal;
    Pair pr;
    pr.thr0 = thresholds[b + g0];
    pr.thrL = thresholds[b + 2 * g0 + 1];
    pr.thrR = thresholds[b + 2 * g0 + 2];
    pr.meta = (unsigned)features[b + g0]
            | ((unsigned)features[b + 2 * g0 + 1] << 6)
            | ((unsigned)features[b + 2 * g0 + 2] << 12);
    pairsA[(t << 9) + e] = pr;
}

__global__ __launch_bounds__(256) void pack_sub_kernel(
    const int* __restrict__ features, const float* __restrict__ thresholds,
    const int* __restrict__ leaf_values, Sub16* __restrict__ subsA)
{
    int i = blockIdx.x * 256 + threadIdx.x;       // over 64*1024
    if (i >= kTrees * 1024) return;
    int t = i >> 10;
    int j = i & 1023;
    int n10 = 1023 + j;
    int b   = t * kInternal;
    Sub16 sb;
    sb.thr10 = thresholds[b + n10];
    sb.thrL  = thresholds[b + 2 * n10 + 1];
    sb.thrR  = thresholds[b + 2 * n10 + 2];
    const int* lv = leaf_values + ((t << 12) + 4 * j);
    sb.meta = (unsigned)features[b + n10]
            | ((unsigned)features[b + 2 * n10 + 1] << 6)
            | ((unsigned)features[b + 2 * n10 + 2] << 12)
            | ((unsigned)lv[0] << 18) | ((unsigned)lv[1] << 21)
            | ((unsigned)lv[2] << 24) | ((unsigned)lv[3] << 27);
    subsA[(t << 10) + j] = sb;
}

__global__ __launch_bounds__(TPB, 8) void forest_kernel(
    const float* __restrict__ X,
    const Pair*  __restrict__ pairsA,
    const Sub16* __restrict__ subsA,
    int* __restrict__ out)
{
    extern __shared__ float xs[];
    const int tid  = threadIdx.x;
    const int s    = tid & (SPB - 1);
    const int h    = tid >> 8;
    const int base = blockIdx.x * SPB;

    {
        const float4* Xr = (const float4*)(X + (size_t)(base + s) * kFeat) + h * 4;
        #pragma unroll
        for (int k = 0; k < 4; ++k) {
            float4 v = Xr[k];
            int f0 = (h * 4 + k) * 4;
            xs[(f0 + 0) * XSTR + s] = v.x;
            xs[(f0 + 1) * XSTR + s] = v.y;
            xs[(f0 + 2) * XSTR + s] = v.z;
            xs[(f0 + 3) * XSTR + s] = v.w;
        }
    }
    __syncthreads();

    const char* xb = (const char*)xs + (s << 2);
    unsigned long long votes = 0ull;
    const int mofs[4] = {0, 1, 5, 21};

    const int tbeg = h * TREES_PER_THREAD;
    for (int t0 = tbeg; t0 < tbeg + TREES_PER_THREAD; t0 += ILP) {
        int m[ILP];
        #pragma unroll
        for (int j = 0; j < ILP; ++j) m[j] = 0;

        #pragma unroll
        for (int p = 0; p < 4; ++p) {
            #pragma unroll
            for (int j = 0; j < ILP; ++j) {
                Pair pr = pairsA[((t0 + j) << 9) + mofs[p] + m[j]];
                float x0 = *(const float*)(xb + ((pr.meta & 63u) << 10));
                int c0 = x0 > pr.thr0 ? 1 : 0;
                float thr1     = c0 ? pr.thrR : pr.thrL;
                unsigned fsel  = c0 ? (pr.meta >> 12) : (pr.meta >> 6);
                float x1 = *(const float*)(xb + ((fsel & 63u) << 10));
                int c1 = x1 > thr1 ? 1 : 0;
                m[j] = 4 * m[j] + 2 * c0 + c1;
            }
        }

        #pragma unroll
        for (int j = 0; j < ILP; ++j) {
            Pair pr = pairsA[((t0 + j) << 9) + 85 + m[j]];
            float x0 = *(const float*)(xb + ((pr.meta & 63u) << 10));
            int c0 = x0 > pr.thr0 ? 1 : 0;
            float thr1     = c0 ? pr.thrR : pr.thrL;
            unsigned fsel  = c0 ? (pr.meta >> 12) : (pr.meta >> 6);
            float x1 = *(const float*)(xb + ((fsel & 63u) << 10));
            int c1 = x1 > thr1 ? 1 : 0;
            m[j] = 4 * m[j] + 2 * c0 + c1;
        }

        #pragma unroll
        for (int j = 0; j < ILP; ++j) {
            Sub16 sb = subsA[((t0 + j) << 10) + m[j]];
            unsigned mt = sb.meta;
            float x0 = *(const float*)(xb + ((mt & 63u) << 10));
            int c0 = x0 > sb.thr10 ? 1 : 0;
            float thr1    = c0 ? sb.thrR : sb.thrL;
            unsigned fsel = c0 ? (mt >> 12) : (mt >> 6);
            float x1 = *(const float*)(xb + ((fsel & 63u) << 10));
            int c1 = x1 > thr1 ? 1 : 0;
            int cls = (mt >> (18 + 3 * ((c0 << 1) | c1))) & 7;
            votes += 1ull << (cls << 3);
        }
    }

    __syncthreads();
    unsigned long long* vbuf = (unsigned long long*)xs;
    if (h != 0) vbuf[(h - 1) * SPB + s] = votes;
    __syncthreads();
    if (h == 0) {
        votes += vbuf[s] + vbuf[SPB + s] + vbuf[2 * SPB + s];
        int best = 0;
        int bc   = (int)(votes & 0xFFull);
        #pragma unroll
        for (int c = 1; c < kClasses; ++c) {
            int cnt = (int)((votes >> (c * 8)) & 0xFFull);
            if (cnt > bc) { bc = cnt; best = c; }
        }
        out[base + s] = best;
    }
}

extern "C" void kernel_launch(void* const* d_in, const int* in_sizes, int n_in,
                              void* d_out, int out_size, void* d_ws, size_t ws_size,
                              hipStream_t stream) {
    const float* X          = (const float*)d_in[0];
    const int*   features   = (const int*)d_in[1];
    const float* thresholds = (const float*)d_in[2];
    const int*   leaves     = (const int*)d_in[3];
    int*         out        = (int*)d_out;

    Pair*  pairsA = (Pair*)d_ws;                            // 64*512*16 = 512 KiB
    Sub16* subsA  = (Sub16*)((char*)d_ws + (kTrees << 13)); // +512 KiB, 1 MiB

    (void)hipFuncSetAttribute((const void*)forest_all,
                              hipFuncAttributeMaxDynamicSharedMemorySize,
                              XLDS_BYTES);
    (void)hipFuncSetAttribute((const void*)forest_kernel,
                              hipFuncAttributeMaxDynamicSharedMemorySize,
                              XLDS_BYTES);

    int maxB = 0;
    (void)hipOccupancyMaxActiveBlocksPerMultiprocessor(
        &maxB, (const void*)forest_all, TPB, XLDS_BYTES);

    if (maxB >= 2) {   // 2 blocks/CU x 256 CUs == NCHUNKS co-resident
        void* args[] = {(void*)&X, (void*)&features, (void*)&thresholds,
                        (void*)&leaves, (void*)&pairsA, (void*)&subsA, (void*)&out};
        hipError_t e = hipLaunchCooperativeKernel((const void*)forest_all,
                                                  dim3(NCHUNKS), dim3(TPB),
                                                  args, (unsigned)XLDS_BYTES, stream);
        if (e == hipSuccess) return;
    }

    // Fallback: original 3-kernel plan.
    pack_pairs_kernel<<<(kTrees * 341 + 255) / 256, 256, 0, stream>>>(
        features, thresholds, pairsA);
    pack_sub_kernel<<<(kTrees * 1024 + 255) / 256, 256, 0, stream>>>(
        features, thresholds, leaves, subsA);
    forest_kernel<<<kSamples / SPB, TPB, XLDS_BYTES, stream>>>(
        X, pairsA, subsA, out);
}